// Round 2
// baseline (416.139 us; speedup 1.0000x reference)
//
#include <hip/hip_runtime.h>

// BMM_S8T_S8N_F16T: out[b,m,n] = fp16(alpha * sum_k A[b,m,k]*B[b,n,k])
// A: (B,M,K) int32 (int8-range), B: (B,N,K) int32, out: float (fp16 ref -> float* buffer)
// B=64, M=N=1024, K=128.
//
// Roofline: 268 MB fp32 write + 67 MB read => ~53 us floor @6.3 TB/s. Write-bound.
// Structure: 128x128 output tile / block (256 thr, 4 waves, 64x64 per wave),
// full K=128 staged packed-int8 in LDS (row stride 144B: 36 dwords -> staging
// writes 2-way alias (free), fragment b128 reads bank-balanced),
// mfma_i32_16x16x64_i8 x 2 K-steps, fp32 epilogue.
//
// R1 lesson: __launch_bounds__(256,4) capped VGPR at 128 < ~160 live in the
// MFMA loop -> accumulator spills to scratch -> 360 us. No waves/EU cap here:
// need ~160-200 VGPR spill-free; LDS 36 KB still permits 4 blocks/CU.

#define Mdim 1024
#define Ndim 1024
#define Kdim 128
#define TILE 128
#define LDS_STRIDE 144  // 128B row + 16B pad (keeps 16B alignment, breaks bank pow2)

using int32x4 = __attribute__((ext_vector_type(4))) int;

__global__ __launch_bounds__(256)
void bmm_s8_kernel(const int* __restrict__ A, const int* __restrict__ Bm,
                   const float* __restrict__ alpha_p, float* __restrict__ out)
{
    __shared__ unsigned char As[TILE * LDS_STRIDE];
    __shared__ unsigned char Bs[TILE * LDS_STRIDE];

    const int t  = threadIdx.x;
    const int n0 = blockIdx.x * TILE;
    const int m0 = blockIdx.y * TILE;
    const int bz = blockIdx.z;

    const int* __restrict__ Ab = A  + (size_t)bz * Mdim * Kdim;
    const int* __restrict__ Bb = Bm + (size_t)bz * Ndim * Kdim;

    // ---- stage global int32 -> packed int8 in LDS ----
    // Tile = 128 rows x 128 k int32 = 4096 int4-chunks; 16 chunks/thread.
    // Chunk f: row = f>>5, element col = (f&31)*4. Per-instruction lanes are
    // 16B-contiguous (f = t + 256*j) -> coalesced 4 KB/wave-instr.
#pragma unroll
    for (int j = 0; j < 16; ++j) {
        const int f    = t + 256 * j;
        const int row  = f >> 5;
        const int colb = (f & 31) * 4;  // int32 col == packed byte offset

        const int32x4 va = *(const int32x4*)(Ab + (size_t)(m0 + row) * Kdim + colb);
        unsigned int pa = (unsigned)(va.x & 255)
                        | ((unsigned)(va.y & 255) << 8)
                        | ((unsigned)(va.z & 255) << 16)
                        | ((unsigned)(va.w & 255) << 24);
        *(unsigned int*)(&As[row * LDS_STRIDE + colb]) = pa;

        const int32x4 vb = *(const int32x4*)(Bb + (size_t)(n0 + row) * Kdim + colb);
        unsigned int pb = (unsigned)(vb.x & 255)
                        | ((unsigned)(vb.y & 255) << 8)
                        | ((unsigned)(vb.z & 255) << 16)
                        | ((unsigned)(vb.w & 255) << 24);
        *(unsigned int*)(&Bs[row * LDS_STRIDE + colb]) = pb;
    }
    __syncthreads();

    // ---- MFMA compute: wave w handles 64x64 sub-tile ----
    const int lane = t & 63;
    const int wave = t >> 6;
    const int wm = (wave >> 1) * 64;
    const int wn = (wave & 1) * 64;

    int32x4 acc[4][4];
#pragma unroll
    for (int mt = 0; mt < 4; ++mt)
#pragma unroll
        for (int nt = 0; nt < 4; ++nt)
            acc[mt][nt] = (int32x4){0, 0, 0, 0};

    // A-operand layout (16x16x64 i8): lane holds row (lane&15), 16 contiguous
    // k-bytes at koff (lane>>4)*16.
    const int lrow = lane & 15;
    const int koff = (lane >> 4) * 16;

#pragma unroll
    for (int ks = 0; ks < 2; ++ks) {
        int32x4 af[4], bf[4];
#pragma unroll
        for (int mt = 0; mt < 4; ++mt)
            af[mt] = *(const int32x4*)(&As[(wm + mt * 16 + lrow) * LDS_STRIDE + ks * 64 + koff]);
#pragma unroll
        for (int nt = 0; nt < 4; ++nt)
            bf[nt] = *(const int32x4*)(&Bs[(wn + nt * 16 + lrow) * LDS_STRIDE + ks * 64 + koff]);
#pragma unroll
        for (int mt = 0; mt < 4; ++mt)
#pragma unroll
            for (int nt = 0; nt < 4; ++nt)
                acc[mt][nt] = __builtin_amdgcn_mfma_i32_16x16x64_i8(
                    af[mt], bf[nt], acc[mt][nt], 0, 0, 0);
    }

    // ---- epilogue: alpha * acc -> fp32 out ----
    // C/D layout (16x16): col = lane&15, row = (lane>>4)*4 + reg  [m89/m121]
    const float alpha = alpha_p[0];
    const int crow = (lane >> 4) * 4;
    const int ccol = lane & 15;
    float* __restrict__ Ob = out + (size_t)bz * Mdim * Ndim;

#pragma unroll
    for (int mt = 0; mt < 4; ++mt)
#pragma unroll
        for (int nt = 0; nt < 4; ++nt) {
            const int n = n0 + wn + nt * 16 + ccol;
            const size_t base = (size_t)(m0 + wm + mt * 16 + crow) * Ndim + n;
#pragma unroll
            for (int r = 0; r < 4; ++r)
                Ob[base + (size_t)r * Ndim] = alpha * (float)acc[mt][nt][r];
        }
}

extern "C" void kernel_launch(void* const* d_in, const int* in_sizes, int n_in,
                              void* d_out, int out_size, void* d_ws, size_t ws_size,
                              hipStream_t stream) {
    const int*   a     = (const int*)d_in[0];
    const int*   b     = (const int*)d_in[1];
    const float* alpha = (const float*)d_in[2];
    float*       out   = (float*)d_out;

    const int batch = in_sizes[0] / (Mdim * Kdim);  // 64
    dim3 grid(Ndim / TILE, Mdim / TILE, batch);
    bmm_s8_kernel<<<grid, 256, 0, stream>>>(a, b, alpha, out);
}

// Round 3
// 401.720 us; speedup vs baseline: 1.0359x; 1.0359x over previous
//
#include <hip/hip_runtime.h>

// BMM_S8T_S8N_F16T: out[b,m,n] = fp16(alpha * sum_k A[b,m,k]*B[b,n,k])
// A: (B,M,K) int32 (int8-range), B: (B,N,K) int32, out: float. B=64, M=N=1024, K=128.
//
// Roofline: 268 MB fp32 write + 67 MB read => ~53 us floor @6.3 TB/s. Write-bound.
// R2: 170 us @2.47 TB/s, write path ~1.8 TB/s — 64 scalar dword stores/thread,
//     4x64B discontiguous segments per wave-instr.
// R3: swap MFMA operands -> D = C^T tile: lane holds m=lane&15 fixed,
//     n=(lane>>4)*4+reg = 4 CONSECUTIVE n -> one float4 store per (mt,nt).
//     16 stores/thread, 16x64B-contiguous segments (1KB) per wave-instr.

#define Mdim 1024
#define Ndim 1024
#define Kdim 128
#define TILE 128
#define LDS_STRIDE 144  // 128B row + 16B pad: staging writes 2-way alias (free),
                        // fragment b128 reads bank-balanced

using int32x4 = __attribute__((ext_vector_type(4))) int;
using floatx4 = __attribute__((ext_vector_type(4))) float;

__global__ __launch_bounds__(256)
void bmm_s8_kernel(const int* __restrict__ A, const int* __restrict__ Bm,
                   const float* __restrict__ alpha_p, float* __restrict__ out)
{
    __shared__ unsigned char As[TILE * LDS_STRIDE];
    __shared__ unsigned char Bs[TILE * LDS_STRIDE];

    const int t  = threadIdx.x;
    const int n0 = blockIdx.x * TILE;
    const int m0 = blockIdx.y * TILE;
    const int bz = blockIdx.z;

    const int* __restrict__ Ab = A  + (size_t)bz * Mdim * Kdim;
    const int* __restrict__ Bb = Bm + (size_t)bz * Ndim * Kdim;

    // ---- stage global int32 -> packed int8 in LDS ----
    // 4096 int4-chunks per tile; 16/thread; lanes 16B-contiguous -> coalesced.
#pragma unroll
    for (int j = 0; j < 16; ++j) {
        const int f    = t + 256 * j;
        const int row  = f >> 5;
        const int colb = (f & 31) * 4;

        const int32x4 va = *(const int32x4*)(Ab + (size_t)(m0 + row) * Kdim + colb);
        unsigned int pa = (unsigned)(va.x & 255)
                        | ((unsigned)(va.y & 255) << 8)
                        | ((unsigned)(va.z & 255) << 16)
                        | ((unsigned)(va.w & 255) << 24);
        *(unsigned int*)(&As[row * LDS_STRIDE + colb]) = pa;

        const int32x4 vb = *(const int32x4*)(Bb + (size_t)(n0 + row) * Kdim + colb);
        unsigned int pb = (unsigned)(vb.x & 255)
                        | ((unsigned)(vb.y & 255) << 8)
                        | ((unsigned)(vb.z & 255) << 16)
                        | ((unsigned)(vb.w & 255) << 24);
        *(unsigned int*)(&Bs[row * LDS_STRIDE + colb]) = pb;
    }
    __syncthreads();

    // ---- MFMA compute: wave handles 64x64 sub-tile ----
    const int lane = t & 63;
    const int wave = t >> 6;
    const int wm = (wave >> 1) * 64;
    const int wn = (wave & 1) * 64;

    int32x4 acc[4][4];
#pragma unroll
    for (int mt = 0; mt < 4; ++mt)
#pragma unroll
        for (int nt = 0; nt < 4; ++nt)
            acc[mt][nt] = (int32x4){0, 0, 0, 0};

    // Operand fragments (both A- and B-side are K-contiguous rows):
    // lane holds row lane&15, 16 k-bytes at (lane>>4)*16.
    const int lrow = lane & 15;
    const int koff = (lane >> 4) * 16;

#pragma unroll
    for (int ks = 0; ks < 2; ++ks) {
        int32x4 af[4], bf[4];
#pragma unroll
        for (int mt = 0; mt < 4; ++mt)
            af[mt] = *(const int32x4*)(&As[(wm + mt * 16 + lrow) * LDS_STRIDE + ks * 64 + koff]);
#pragma unroll
        for (int nt = 0; nt < 4; ++nt)
            bf[nt] = *(const int32x4*)(&Bs[(wn + nt * 16 + lrow) * LDS_STRIDE + ks * 64 + koff]);
        // SWAPPED operands: D = (B-rows)x(A-cols) = C^T sub-tile.
        // D layout: col(lane&15)=m_local, row((lane>>4)*4+reg)=n_local.
#pragma unroll
        for (int mt = 0; mt < 4; ++mt)
#pragma unroll
            for (int nt = 0; nt < 4; ++nt)
                acc[mt][nt] = __builtin_amdgcn_mfma_i32_16x16x64_i8(
                    bf[nt], af[mt], acc[mt][nt], 0, 0, 0);
    }

    // ---- epilogue: alpha * acc -> fp32 out, float4 per (mt,nt) ----
    const float alpha = alpha_p[0];
    const int cm = lane & 15;        // m within 16-tile
    const int cn = (lane >> 4) * 4;  // n within 16-tile, 4 consecutive via reg
    float* __restrict__ Ob = out + (size_t)bz * Mdim * Ndim;

#pragma unroll
    for (int mt = 0; mt < 4; ++mt) {
        const size_t rowbase = (size_t)(m0 + wm + mt * 16 + cm) * Ndim;
#pragma unroll
        for (int nt = 0; nt < 4; ++nt) {
            const int col = n0 + wn + nt * 16 + cn;
            floatx4 v;
            v.x = alpha * (float)acc[mt][nt][0];
            v.y = alpha * (float)acc[mt][nt][1];
            v.z = alpha * (float)acc[mt][nt][2];
            v.w = alpha * (float)acc[mt][nt][3];
            *(floatx4*)(Ob + rowbase + col) = v;
        }
    }
}

extern "C" void kernel_launch(void* const* d_in, const int* in_sizes, int n_in,
                              void* d_out, int out_size, void* d_ws, size_t ws_size,
                              hipStream_t stream) {
    const int*   a     = (const int*)d_in[0];
    const int*   b     = (const int*)d_in[1];
    const float* alpha = (const float*)d_in[2];
    float*       out   = (float*)d_out;

    const int batch = in_sizes[0] / (Mdim * Kdim);  // 64
    dim3 grid(Ndim / TILE, Mdim / TILE, batch);
    bmm_s8_kernel<<<grid, 256, 0, stream>>>(a, b, alpha, out);
}

// Round 4
// 348.236 us; speedup vs baseline: 1.1950x; 1.1536x over previous
//
#include <hip/hip_runtime.h>

// BMM_S8T_S8N_F16T: out[b,m,n] = fp16(alpha * sum_k A[b,m,k]*B[b,n,k])
// A: (B,M,K) int32 (int8-range), B: (B,N,K) int32, out: float. B=64, M=N=1024, K=128.
//
// Roofline: 263 MB write + ~67 MB read => ~53 us @6.3 TB/s. Memory-bound.
// R2/R3: 4096 short blocks (stage->barrier->32 MFMA->store->die) = 170 us,
//   2.45 TB/s, everything idle -> latency/phase bound, NOT store-width bound
//   (float4 epilogue changed nothing). FETCH 147 MB (2.2x ideal): A-tile
//   sharers spread across non-coherent XCD L2s.
// R4: persistent row-stripe blocks. Block = (z, m_tile); A-tile staged once;
//   loop 8 n-tiles with B double-buffered via registers -- next tile's 16x16B
//   loads issued before MFMA/store of current -> global latency overlapped.
//   512 blocks = 2/CU, whole grid co-resident. Grid (64,8): linear%8 = z%8
//   -> all blocks of batch z on one XCD -> B tiles hit in L2, A read once.

#define Mdim 1024
#define Ndim 1024
#define Kdim 128
#define TILE 128
#define LDS_STRIDE 144  // 128B row + 16B pad; staging 2-way alias free, b128 reads balanced

using int32x4 = __attribute__((ext_vector_type(4))) int;
using floatx4 = __attribute__((ext_vector_type(4))) float;

__device__ __forceinline__ unsigned pack8(int32x4 v) {
    return (unsigned)(v.x & 255) | ((unsigned)(v.y & 255) << 8)
         | ((unsigned)(v.z & 255) << 16) | ((unsigned)(v.w & 255) << 24);
}

__global__ __launch_bounds__(256)
void bmm_s8_kernel(const int* __restrict__ A, const int* __restrict__ Bm,
                   const float* __restrict__ alpha_p, float* __restrict__ out)
{
    __shared__ unsigned char As[TILE * LDS_STRIDE];
    __shared__ unsigned char Bs[2][TILE * LDS_STRIDE];

    const int t      = threadIdx.x;
    const int z      = blockIdx.x;   // batch: linear%8 = z%8 -> per-XCD batch affinity
    const int m_tile = blockIdx.y;
    const int m0     = m_tile * TILE;

    const int* __restrict__ Ab = A  + (size_t)z * Mdim * Kdim + (size_t)m0 * Kdim;
    const int* __restrict__ Bb = Bm + (size_t)z * Ndim * Kdim;

    // Per-chunk geometry: chunk f covers row f>>5, int32 cols (f&31)*4..+3.
    const int lane = t & 63;
    const int wave = t >> 6;

    // ---- stage A tile once (128 rows x 128 k) ----
#pragma unroll
    for (int j = 0; j < 16; ++j) {
        const int f    = t + 256 * j;
        const int row  = f >> 5;
        const int colb = (f & 31) * 4;
        const int32x4 va = *(const int32x4*)(Ab + (size_t)row * Kdim + colb);
        *(unsigned*)(&As[row * LDS_STRIDE + colb]) = pack8(va);
    }

    // ---- prologue: load B tile 0 into registers ----
    int32x4 breg[16];
#pragma unroll
    for (int j = 0; j < 16; ++j) {
        const int f    = t + 256 * j;
        const int row  = f >> 5;
        const int colb = (f & 31) * 4;
        breg[j] = *(const int32x4*)(Bb + (size_t)row * Kdim + colb);
    }

    const float alpha = alpha_p[0];
    const int wm   = (wave >> 1) * 64;
    const int wn   = (wave & 1) * 64;
    const int lrow = lane & 15;
    const int koff = (lane >> 4) * 16;
    const int cm   = lane & 15;        // epilogue: m within 16-tile (D col)
    const int cn   = (lane >> 4) * 4;  // epilogue: n base within 16-tile (D rows)
    float* __restrict__ Ob = out + (size_t)z * Mdim * Ndim;

    for (int ni = 0; ni < 8; ++ni) {
        const int buf = ni & 1;
        // pack current B regs -> LDS buf
#pragma unroll
        for (int j = 0; j < 16; ++j) {
            const int f    = t + 256 * j;
            const int row  = f >> 5;
            const int colb = (f & 31) * 4;
            *(unsigned*)(&Bs[buf][row * LDS_STRIDE + colb]) = pack8(breg[j]);
        }
        // issue next tile's loads (in flight across MFMA + stores below)
        if (ni < 7) {
            const int* __restrict__ Bt = Bb + (size_t)(ni + 1) * TILE * Kdim;
#pragma unroll
            for (int j = 0; j < 16; ++j) {
                const int f    = t + 256 * j;
                const int row  = f >> 5;
                const int colb = (f & 31) * 4;
                breg[j] = *(const int32x4*)(Bt + (size_t)row * Kdim + colb);
            }
        }
        __syncthreads();  // covers A-stage (ni=0), B producer->consumer, dist-2 reuse

        // ---- MFMA: wave computes 64x64 of the 128(m) x 128(n) tile ----
        int32x4 acc[4][4];
#pragma unroll
        for (int mt = 0; mt < 4; ++mt)
#pragma unroll
            for (int nt = 0; nt < 4; ++nt)
                acc[mt][nt] = (int32x4){0, 0, 0, 0};

#pragma unroll
        for (int ks = 0; ks < 2; ++ks) {
            int32x4 af[4], bf[4];
#pragma unroll
            for (int mt = 0; mt < 4; ++mt)
                af[mt] = *(const int32x4*)(&As[(wm + mt * 16 + lrow) * LDS_STRIDE + ks * 64 + koff]);
#pragma unroll
            for (int nt = 0; nt < 4; ++nt)
                bf[nt] = *(const int32x4*)(&Bs[buf][(wn + nt * 16 + lrow) * LDS_STRIDE + ks * 64 + koff]);
            // swapped operands: D holds m in cols (lane&15), 4 consecutive n in regs
#pragma unroll
            for (int mt = 0; mt < 4; ++mt)
#pragma unroll
                for (int nt = 0; nt < 4; ++nt)
                    acc[mt][nt] = __builtin_amdgcn_mfma_i32_16x16x64_i8(
                        bf[nt], af[mt], acc[mt][nt], 0, 0, 0);
        }

        // ---- epilogue: float4 stores ----
#pragma unroll
        for (int mt = 0; mt < 4; ++mt) {
            const size_t rowbase = (size_t)(m0 + wm + mt * 16 + cm) * Ndim;
#pragma unroll
            for (int nt = 0; nt < 4; ++nt) {
                const int col = ni * TILE + wn + nt * 16 + cn;
                floatx4 v;
                v.x = alpha * (float)acc[mt][nt][0];
                v.y = alpha * (float)acc[mt][nt][1];
                v.z = alpha * (float)acc[mt][nt][2];
                v.w = alpha * (float)acc[mt][nt][3];
                *(floatx4*)(Ob + rowbase + col) = v;
            }
        }
        // no trailing barrier: dist-2 LDS reuse is covered by next iter's barrier
    }
}

extern "C" void kernel_launch(void* const* d_in, const int* in_sizes, int n_in,
                              void* d_out, int out_size, void* d_ws, size_t ws_size,
                              hipStream_t stream) {
    const int*   a     = (const int*)d_in[0];
    const int*   b     = (const int*)d_in[1];
    const float* alpha = (const float*)d_in[2];
    float*       out   = (float*)d_out;

    const int batch = in_sizes[0] / (Mdim * Kdim);  // 64
    dim3 grid(batch, Mdim / TILE);                  // (64, 8): linear%8 == z%8
    bmm_s8_kernel<<<grid, 256, 0, stream>>>(a, b, alpha, out);
}

// Round 5
// 346.972 us; speedup vs baseline: 1.1993x; 1.0036x over previous
//
#include <hip/hip_runtime.h>

// BMM_S8T_S8N_F16T: out[b,m,n] = fp16(alpha * sum_k A[b,m,k]*B[b,n,k])
// A: (B,M,K) int32 (int8-range), B: (B,N,K) int32, out: float. B=64, M=N=1024, K=128.
//
// Roofline: 263 MB write + 67 MB read => ~53 us @6.3 TB/s. Write-dominated.
// R2/R3: grid-per-tile, 170 us; latency/phase-bound (float4 stores changed nothing).
// R4: persistent row-stripe + reg prefetch = ~116 us. BUT prefetch was issued
//   BEFORE __syncthreads, and the compiler emits s_waitcnt vmcnt(0) before
//   s_barrier -> the 64 KB tile load was fully drained at each barrier. No
//   read/compute/store overlap.
// R5: loads AFTER the barrier. Per iter: barrier -> issue B(ni+1) loads ->
//   MFMA (LDS deps only) -> float4 stores -> pack breg->LDS (vmcnt via data
//   dep). Loads are in flight during MFMA+stores; barrier end-of-iter waits
//   only LDS writes + store-ack at L2. unroll 1 keeps loads below the barrier.

#define Mdim 1024
#define Ndim 1024
#define Kdim 128
#define TILE 128
#define LDS_STRIDE 144  // 128B row + 16B pad; staging 2-way alias free, b128 16B-aligned

using int32x4 = __attribute__((ext_vector_type(4))) int;
using floatx4 = __attribute__((ext_vector_type(4))) float;

__device__ __forceinline__ unsigned pack8(int32x4 v) {
    return (unsigned)(v.x & 255) | ((unsigned)(v.y & 255) << 8)
         | ((unsigned)(v.z & 255) << 16) | ((unsigned)(v.w & 255) << 24);
}

__global__ __launch_bounds__(256)
void bmm_s8_kernel(const int* __restrict__ A, const int* __restrict__ Bm,
                   const float* __restrict__ alpha_p, float* __restrict__ out)
{
    __shared__ unsigned char As[TILE * LDS_STRIDE];
    __shared__ unsigned char Bs[2][TILE * LDS_STRIDE];

    const int t      = threadIdx.x;
    const int z      = blockIdx.x;   // batch; linear%8 == z%8 -> per-XCD batch affinity
    const int m_tile = blockIdx.y;
    const int m0     = m_tile * TILE;

    const int* __restrict__ Ab = A  + (size_t)z * Mdim * Kdim + (size_t)m0 * Kdim;
    const int* __restrict__ Bb = Bm + (size_t)z * Ndim * Kdim;

    const int lane = t & 63;
    const int wave = t >> 6;

    // chunk f: row f>>5, int32 col (f&31)*4; lanes 16B-contiguous -> coalesced
    const int s_row  = (t + 0) >> 5;       // reused geometry per j via f = t+256j
    (void)s_row;

    // ---- prologue: stage A tile + B tile 0 ----
    {
        int32x4 areg[16], breg[16];
#pragma unroll
        for (int j = 0; j < 16; ++j) {
            const int f    = t + 256 * j;
            const int row  = f >> 5;
            const int colb = (f & 31) * 4;
            areg[j] = *(const int32x4*)(Ab + (size_t)row * Kdim + colb);
            breg[j] = *(const int32x4*)(Bb + (size_t)row * Kdim + colb);
        }
#pragma unroll
        for (int j = 0; j < 16; ++j) {
            const int f    = t + 256 * j;
            const int row  = f >> 5;
            const int colb = (f & 31) * 4;
            *(unsigned*)(&As[row * LDS_STRIDE + colb])    = pack8(areg[j]);
            *(unsigned*)(&Bs[0][row * LDS_STRIDE + colb]) = pack8(breg[j]);
        }
    }
    __syncthreads();

    const float alpha = alpha_p[0];
    const int wm   = (wave >> 1) * 64;
    const int wn   = (wave & 1) * 64;
    const int lrow = lane & 15;
    const int koff = (lane >> 4) * 16;
    const int cm   = lane & 15;        // D col = m_local
    const int cn   = (lane >> 4) * 4;  // D rows = 4 consecutive n_local
    float* __restrict__ Ob = out + (size_t)z * Mdim * Ndim;

#pragma unroll 1
    for (int ni = 0; ni < 8; ++ni) {
        const int buf = ni & 1;

        // ---- issue next B tile's loads (AFTER the barrier -> stay in flight
        //      across MFMA + stores below) ----
        int32x4 breg[16];
        if (ni < 7) {
            const int* __restrict__ Bt = Bb + (size_t)(ni + 1) * TILE * Kdim;
#pragma unroll
            for (int j = 0; j < 16; ++j) {
                const int f    = t + 256 * j;
                const int row  = f >> 5;
                const int colb = (f & 31) * 4;
                breg[j] = *(const int32x4*)(Bt + (size_t)row * Kdim + colb);
            }
        }

        // ---- MFMA: wave computes 64(m) x 64(n) of this tile ----
        int32x4 acc[4][4];
#pragma unroll
        for (int mt = 0; mt < 4; ++mt)
#pragma unroll
            for (int nt = 0; nt < 4; ++nt)
                acc[mt][nt] = (int32x4){0, 0, 0, 0};

#pragma unroll
        for (int ks = 0; ks < 2; ++ks) {
            int32x4 af[4], bf[4];
#pragma unroll
            for (int mt = 0; mt < 4; ++mt)
                af[mt] = *(const int32x4*)(&As[(wm + mt * 16 + lrow) * LDS_STRIDE + ks * 64 + koff]);
#pragma unroll
            for (int nt = 0; nt < 4; ++nt)
                bf[nt] = *(const int32x4*)(&Bs[buf][(wn + nt * 16 + lrow) * LDS_STRIDE + ks * 64 + koff]);
            // swapped operands: D holds m in cols (lane&15), 4 consecutive n in regs
#pragma unroll
            for (int mt = 0; mt < 4; ++mt)
#pragma unroll
                for (int nt = 0; nt < 4; ++nt)
                    acc[mt][nt] = __builtin_amdgcn_mfma_i32_16x16x64_i8(
                        bf[nt], af[mt], acc[mt][nt], 0, 0, 0);
        }

        // ---- epilogue: float4 stores ----
#pragma unroll
        for (int mt = 0; mt < 4; ++mt) {
            const size_t rowbase = (size_t)(m0 + wm + mt * 16 + cm) * Ndim;
#pragma unroll
            for (int nt = 0; nt < 4; ++nt) {
                const int col = ni * TILE + wn + nt * 16 + cn;
                floatx4 v;
                v.x = alpha * (float)acc[mt][nt][0];
                v.y = alpha * (float)acc[mt][nt][1];
                v.z = alpha * (float)acc[mt][nt][2];
                v.w = alpha * (float)acc[mt][nt][3];
                *(floatx4*)(Ob + rowbase + col) = v;
            }
        }

        // ---- consume prefetch: pack into the other LDS buffer (vmcnt wait
        //      happens HERE, after MFMA+stores already issued) ----
        if (ni < 7) {
#pragma unroll
            for (int j = 0; j < 16; ++j) {
                const int f    = t + 256 * j;
                const int row  = f >> 5;
                const int colb = (f & 31) * 4;
                *(unsigned*)(&Bs[buf ^ 1][row * LDS_STRIDE + colb]) = pack8(breg[j]);
            }
        }
        __syncthreads();
    }
}

extern "C" void kernel_launch(void* const* d_in, const int* in_sizes, int n_in,
                              void* d_out, int out_size, void* d_ws, size_t ws_size,
                              hipStream_t stream) {
    const int*   a     = (const int*)d_in[0];
    const int*   b     = (const int*)d_in[1];
    const float* alpha = (const float*)d_in[2];
    float*       out   = (float*)d_out;

    const int batch = in_sizes[0] / (Mdim * Kdim);  // 64
    dim3 grid(batch, Mdim / TILE);                  // (64, 8): linear%8 == z%8
    bmm_s8_kernel<<<grid, 256, 0, stream>>>(a, b, alpha, out);
}